// Round 13
// baseline (369.843 us; speedup 1.0000x reference)
//
#include <hip/hip_runtime.h>
#include <hip/hip_bf16.h>

#define NN 50000
#define NE 400000
#define NPAIR 12500        // NE/32: 32 sorted edges per wave-iteration
#define NPAD 50176         // 1024*49 scan domain

typedef __bf16 bf16_t;
typedef __bf16 bf16x4 __attribute__((ext_vector_type(4)));
typedef __bf16 bf16x8 __attribute__((ext_vector_type(8)));
typedef float  floatx4 __attribute__((ext_vector_type(4)));

static __device__ __forceinline__ floatx4 mfma16(bf16x8 a, bf16x8 b, floatx4 c) {
    return __builtin_amdgcn_mfma_f32_16x16x32_bf16(a, b, c, 0, 0, 0);
}
static __device__ __forceinline__ float sigm_f(float x) {
    return 1.f / (1.f + __expf(-x));
}
static __device__ __forceinline__ float tanh_f(float x) {
    return 1.f - 2.f / (__expf(2.f * x) + 1.f);
}
static __device__ __forceinline__ bf16x8 cvt8(const float* sp) {
    float4 f0 = *(const float4*)sp;
    float4 f1 = *(const float4*)(sp + 4);
    bf16x8 v;
    v[0] = (bf16_t)f0.x; v[1] = (bf16_t)f0.y; v[2] = (bf16_t)f0.z; v[3] = (bf16_t)f0.w;
    v[4] = (bf16_t)f1.x; v[5] = (bf16_t)f1.y; v[6] = (bf16_t)f1.z; v[7] = (bf16_t)f1.w;
    return v;
}

// ---------------------------------------------------------------------------
// prep (fused: hb copy + weight transforms + edge histogram).
// deg must be zeroed before this kernel (memset precedes in-stream).
// ---------------------------------------------------------------------------
__global__ __launch_bounds__(256) void prep_kernel(
    const float* __restrict__ nf,
    const float* __restrict__ Wm1, const float* __restrict__ Wm2,
    const float* __restrict__ Wx,  const float* __restrict__ Wh,
    const float* __restrict__ Wr1, const int* __restrict__ edst,
    bf16_t* __restrict__ hb,
    bf16_t* __restrict__ W1f, bf16_t* __restrict__ W2f,
    bf16_t* __restrict__ Wxt, bf16_t* __restrict__ Wht,
    bf16_t* __restrict__ Wr1f, int* __restrict__ deg)
{
    int u = blockIdx.x * 256 + threadIdx.x;
    if (u < 800000) {          // hb: 4 elems per thread
        float4 v = *(const float4*)(nf + (size_t)u * 4);
        bf16x4 o;
        o[0] = (bf16_t)v.x; o[1] = (bf16_t)v.y; o[2] = (bf16_t)v.z; o[3] = (bf16_t)v.w;
        *(bf16x4*)(hb + (size_t)u * 4) = o;
        return;
    }
    u -= 800000;
    if (u < 20480) {
        int j = u & 7, l = (u >> 3) & 63, rem = u >> 9;   // rem 0..39
        int ks = rem % 5, nt = rem / 5;
        int n = nt * 16 + (l & 15);
        int k = ks * 32 + (l >> 4) * 8 + j;
        W1f[u] = (k < 136) ? (bf16_t)Wm1[k * 128 + n] : (bf16_t)0.f;
        return;
    }
    u -= 20480;
    if (u < 8192) {
        int j = u & 7, l = (u >> 3) & 63, rem = u >> 9;   // rem 0..15
        int kg = rem & 3, nt = rem >> 2;
        int n = nt * 16 + (l & 15);
        int k = kg * 32 + (l >> 4) * 8 + j;
        W2f[u] = (bf16_t)Wm2[k * 64 + n];
        return;
    }
    u -= 8192;
    if (u < 12288) {
        int n = u >> 6, k = u & 63;
        Wxt[u] = (bf16_t)Wx[k * 192 + n];
        return;
    }
    u -= 12288;
    if (u < 12288) {
        int n = u >> 6, k = u & 63;
        Wht[u] = (bf16_t)Wh[k * 192 + n];
        return;
    }
    u -= 12288;
    if (u < 8192) {            // Wr1f
        int j = u & 7, l = (u >> 3) & 63, rem = u >> 9;   // rem 0..15
        int kg = rem & 1, nt = rem >> 1;
        int n = nt * 16 + (l & 15);
        int k = kg * 32 + (l >> 4) * 8 + j;
        Wr1f[u] = (bf16_t)Wr1[k * 128 + n];
        return;
    }
    u -= 8192;
    if (u < NE) atomicAdd(&deg[edst[u]], 1);   // histogram
}

// ---------------------------------------------------------------------------
// single-dispatch exclusive scan of deg[NPAD] -> cursor (1 block, 1024 thr,
// 49 contiguous elems/thread; two-pass over deg to avoid register caching).
// ---------------------------------------------------------------------------
__global__ __launch_bounds__(1024) void scan_kernel(
    const int* __restrict__ deg, int* __restrict__ cursor)
{
    __shared__ int part[1024];
    const int t = threadIdx.x;
    const int base = t * 49;
    int sum = 0;
    #pragma unroll 1
    for (int i = 0; i < 49; i++) sum += deg[base + i];
    part[t] = sum;
    __syncthreads();
    for (int st = 1; st < 1024; st <<= 1) {
        int add = (t >= st) ? part[t - st] : 0;
        __syncthreads();
        part[t] += add;
        __syncthreads();
    }
    int run = part[t] - sum;   // exclusive prefix of this chunk
    #pragma unroll 1
    for (int i = 0; i < 49; i++) {
        int d = deg[base + i];
        cursor[base + i] = run;
        run += d;
    }
}

// ---------------------------------------------------------------------------
// scatter: permute srcs/dsts/ef->bf16 into dst-sorted order.
// cursor ends at row-end offsets (gru uses end-deg for start).
// ---------------------------------------------------------------------------
__global__ __launch_bounds__(256) void scatter_kernel(
    const int* __restrict__ esrc, const int* __restrict__ edst,
    const float* __restrict__ ef,
    int* __restrict__ cursor, int* __restrict__ srcs, int* __restrict__ dsts,
    bf16_t* __restrict__ efpb)
{
    int e = blockIdx.x * 256 + threadIdx.x;
    if (e >= NE) return;
    int d = edst[e];
    int p = atomicAdd(&cursor[d], 1);
    srcs[p] = esrc[e];
    dsts[p] = d;
    float4 a = *(const float4*)(ef + (size_t)e * 8);
    float4 b = *(const float4*)(ef + (size_t)e * 8 + 4);
    bf16x8 v;
    v[0] = (bf16_t)a.x; v[1] = (bf16_t)a.y; v[2] = (bf16_t)a.z; v[3] = (bf16_t)a.w;
    v[4] = (bf16_t)b.x; v[5] = (bf16_t)b.y; v[6] = (bf16_t)b.z; v[7] = (bf16_t)b.w;
    *(bf16x8*)(efpb + (size_t)p * 8) = v;
}

// ---------------------------------------------------------------------------
// edge kernel (R12, unchanged): zero atomics, bf16 m stores in sorted order.
// ---------------------------------------------------------------------------
__global__ __launch_bounds__(256) void edge_kernel(
    const bf16_t* __restrict__ hb, const bf16_t* __restrict__ efpb,
    const int* __restrict__ srcs, const int* __restrict__ dsts,
    const bf16_t* __restrict__ W1f, const bf16_t* __restrict__ W2f,
    const float* __restrict__ b1f, const float* __restrict__ b2f,
    bf16_t* __restrict__ mb)
{
    __shared__ __attribute__((aligned(16))) bf16_t w1s[20480];      // 40960 B
    __shared__ __attribute__((aligned(16))) bf16_t w2s[8192];       // 16384 B
    __shared__ __attribute__((aligned(16))) bf16_t hq[4][32 * 36];  //  9216 B

    const int tid = threadIdx.x;
    {
        const uint4* s1 = (const uint4*)W1f;
        uint4* d1 = (uint4*)w1s;
        #pragma unroll
        for (int i = 0; i < 10; i++) d1[tid + i * 256] = s1[tid + i * 256];
        const uint4* s2 = (const uint4*)W2f;
        uint4* d2 = (uint4*)w2s;
        #pragma unroll
        for (int i = 0; i < 4; i++) d2[tid + i * 256] = s2[tid + i * 256];
    }
    __syncthreads();

    const int lane = tid & 63;
    const int wv   = tid >> 6;
    const int l15  = lane & 15;
    const int quad = lane >> 4;

    float b1r[8], b2r[4];
    #pragma unroll
    for (int nt = 0; nt < 8; nt++) b1r[nt] = b1f[nt * 16 + l15];
    #pragma unroll
    for (int nt = 0; nt < 4; nt++) b2r[nt] = b2f[nt * 16 + l15];

    const int WTOT = gridDim.x * 4;
    int p = blockIdx.x * 4 + wv;

    bf16x8 af0[5], af1[5];
    {
        int base = p * 32;
        int r0 = base + l15, r1 = base + 16 + l15;
        int si0 = srcs[r0], di0 = dsts[r0];
        int si1 = srcs[r1], di1 = dsts[r1];
        const bf16_t* sp0 = hb + (size_t)si0 * 64 + quad * 8;
        const bf16_t* dp0 = hb + (size_t)di0 * 64 + quad * 8;
        const bf16_t* sp1 = hb + (size_t)si1 * 64 + quad * 8;
        const bf16_t* dp1 = hb + (size_t)di1 * 64 + quad * 8;
        af0[0] = *(const bf16x8*)sp0;  af0[1] = *(const bf16x8*)(sp0 + 32);
        af0[2] = *(const bf16x8*)dp0;  af0[3] = *(const bf16x8*)(dp0 + 32);
        af1[0] = *(const bf16x8*)sp1;  af1[1] = *(const bf16x8*)(sp1 + 32);
        af1[2] = *(const bf16x8*)dp1;  af1[3] = *(const bf16x8*)(dp1 + 32);
        if (quad == 0) {
            af0[4] = *(const bf16x8*)(efpb + (size_t)r0 * 8);
            af1[4] = *(const bf16x8*)(efpb + (size_t)r1 * 8);
        } else {
            #pragma unroll
            for (int q = 0; q < 8; q++) { af0[4][q] = (bf16_t)0.f; af1[4][q] = (bf16_t)0.f; }
        }
    }

    while (true) {
        int pn = p + WTOT;
        int pp = (pn < NPAIR) ? pn : p;
        int nbase = pp * 32;
        int nr0 = nbase + l15, nr1 = nbase + 16 + l15;
        int si0n = srcs[nr0], di0n = dsts[nr0];
        int si1n = srcs[nr1], di1n = dsts[nr1];

        floatx4 oa0[4], oa1[4];
        #pragma unroll
        for (int nt = 0; nt < 4; nt++) {
            oa0[nt].x=0.f; oa0[nt].y=0.f; oa0[nt].z=0.f; oa0[nt].w=0.f;
            oa1[nt].x=0.f; oa1[nt].y=0.f; oa1[nt].z=0.f; oa1[nt].w=0.f;
        }

        #pragma unroll
        for (int q = 0; q < 4; q++) {
            floatx4 ac0[2], ac1[2];
            #pragma unroll
            for (int nt = 0; nt < 2; nt++) {
                ac0[nt].x=0.f; ac0[nt].y=0.f; ac0[nt].z=0.f; ac0[nt].w=0.f;
                ac1[nt].x=0.f; ac1[nt].y=0.f; ac1[nt].z=0.f; ac1[nt].w=0.f;
            }
            #pragma unroll
            for (int nt = 0; nt < 2; nt++) {
                int gnt = q * 2 + nt;
                #pragma unroll
                for (int ks = 0; ks < 5; ks++) {
                    bf16x8 b = *(const bf16x8*)(w1s + ((gnt * 5 + ks) * 64 + lane) * 8);
                    ac0[nt] = mfma16(af0[ks], b, ac0[nt]);
                    ac1[nt] = mfma16(af1[ks], b, ac1[nt]);
                }
            }
            #pragma unroll
            for (int nt = 0; nt < 2; nt++) {
                float bb = b1r[q * 2 + nt];
                #pragma unroll
                for (int r = 0; r < 4; r++) {
                    float v0 = fmaxf(ac0[nt][r] + bb, 0.f);
                    float v1 = fmaxf(ac1[nt][r] + bb, 0.f);
                    hq[wv][(quad * 4 + r) * 36 + nt * 16 + l15]      = (bf16_t)v0;
                    hq[wv][(16 + quad * 4 + r) * 36 + nt * 16 + l15] = (bf16_t)v1;
                }
            }
            bf16x8 hf0 = *(const bf16x8*)(hq[wv] + l15 * 36 + quad * 8);
            bf16x8 hf1 = *(const bf16x8*)(hq[wv] + (16 + l15) * 36 + quad * 8);
            #pragma unroll
            for (int nt = 0; nt < 4; nt++) {
                bf16x8 w2 = *(const bf16x8*)(w2s + ((nt * 4 + q) * 64 + lane) * 8);
                oa0[nt] = mfma16(hf0, w2, oa0[nt]);
                oa1[nt] = mfma16(hf1, w2, oa1[nt]);
            }
        }

        // prefetch next-pair A fragments BEFORE the store epilogue
        int base = p * 32;
        {
            const bf16_t* sp0 = hb + (size_t)si0n * 64 + quad * 8;
            const bf16_t* dp0 = hb + (size_t)di0n * 64 + quad * 8;
            const bf16_t* sp1 = hb + (size_t)si1n * 64 + quad * 8;
            const bf16_t* dp1 = hb + (size_t)di1n * 64 + quad * 8;
            af0[0] = *(const bf16x8*)sp0;  af0[1] = *(const bf16x8*)(sp0 + 32);
            af0[2] = *(const bf16x8*)dp0;  af0[3] = *(const bf16x8*)(dp0 + 32);
            af1[0] = *(const bf16x8*)sp1;  af1[1] = *(const bf16x8*)(sp1 + 32);
            af1[2] = *(const bf16x8*)dp1;  af1[3] = *(const bf16x8*)(dp1 + 32);
            if (quad == 0) {
                af0[4] = *(const bf16x8*)(efpb + (size_t)nr0 * 8);
                af1[4] = *(const bf16x8*)(efpb + (size_t)nr1 * 8);
            }
        }

        #pragma unroll
        for (int nt = 0; nt < 4; nt++) {
            int col = nt * 16 + l15;
            float bb = b2r[nt];
            #pragma unroll
            for (int r = 0; r < 4; r++) {
                int row0 = base + quad * 4 + r;
                int row1 = base + 16 + quad * 4 + r;
                mb[(size_t)row0 * 64 + col] = (bf16_t)(oa0[nt][r] + bb);
                mb[(size_t)row1 * 64 + col] = (bf16_t)(oa1[nt][r] + bb);
            }
        }

        if (pn >= NPAIR) break;
        p = pn;
    }
}

// ---------------------------------------------------------------------------
// GRU (MFMA) with FUSED CSR gather-sum: each lane sums its node's contiguous
// sorted mb rows (fp32 accumulate, 2x16B loads/row, L3-hot) — replaces the
// separate agg kernel + aggb round-trip. 64 nodes/block, 16/wave.
// LAST=0: h source fp32 (nf), emits bf16 hb only (fp32 h dropped: bf16 h
// adds <=0.4% rel on hold, within the 2% budget). LAST=1: h source bf16 hb,
// fused readout MLP -> out.
// ---------------------------------------------------------------------------
template<int LAST>
__global__ __launch_bounds__(256) void gru_kernel(
    const bf16_t* __restrict__ mb, const int* __restrict__ deg,
    const int* __restrict__ cursor,
    const float* __restrict__ hf, const bf16_t* __restrict__ hbin,
    bf16_t* __restrict__ hb_out,
    const bf16_t* __restrict__ Wxt, const bf16_t* __restrict__ Wht,
    const float* __restrict__ bg,
    const bf16_t* __restrict__ Wr1f, const float* __restrict__ br1,
    const float* __restrict__ Wr2, const float* __restrict__ br2,
    float* __restrict__ out)
{
    __shared__ __attribute__((aligned(16))) float  shd[64 * 68];    // 17408 B
    __shared__ __attribute__((aligned(16))) bf16_t hb2[4][16 * 72]; //  9216 B
    const int tid = threadIdx.x;
    const int n0  = blockIdx.x * 64;

    for (int idx = tid; idx < 64 * 16; idx += 256) {
        int i = idx >> 4, c = (idx & 15) * 4;
        int n = n0 + i; if (n >= NN) n = NN - 1;
        if (LAST == 0) {
            *(float4*)&shd[i * 68 + c] = *(const float4*)(hf + (size_t)n * 64 + c);
        } else {
            bf16x4 v = *(const bf16x4*)(hbin + (size_t)n * 64 + c);
            shd[i * 68 + c + 0] = (float)v[0];
            shd[i * 68 + c + 1] = (float)v[1];
            shd[i * 68 + c + 2] = (float)v[2];
            shd[i * 68 + c + 3] = (float)v[3];
        }
    }
    __syncthreads();

    const int lane = tid & 63;
    const int wv   = tid >> 6;
    const int l15  = lane & 15;
    const int quad = lane >> 4;
    const int rowA = wv * 16 + l15;
    int nA = n0 + rowA; if (nA >= NN) nA = NN - 1;

    // ---- fused CSR gather-sum: agg[nA][quad*8..] and [32+quad*8..] ----
    bf16x8 ax[2];
    {
        int en = cursor[nA];
        int st = en - deg[nA];
        float fa0[8], fa1[8];
        #pragma unroll
        for (int j = 0; j < 8; j++) { fa0[j] = 0.f; fa1[j] = 0.f; }
        #pragma unroll 1
        for (int e = st; e < en; e++) {
            bf16x8 v0 = *(const bf16x8*)(mb + (size_t)e * 64 + quad * 8);
            bf16x8 v1 = *(const bf16x8*)(mb + (size_t)e * 64 + 32 + quad * 8);
            #pragma unroll
            for (int j = 0; j < 8; j++) {
                fa0[j] += (float)v0[j];
                fa1[j] += (float)v1[j];
            }
        }
        #pragma unroll
        for (int j = 0; j < 8; j++) {
            ax[0][j] = (bf16_t)fa0[j];
            ax[1][j] = (bf16_t)fa1[j];
        }
    }

    bf16x8 ah[2];
    {
        const float* hp = shd + rowA * 68 + quad * 8;
        ah[0] = cvt8(hp);
        ah[1] = cvt8(hp + 32);
    }

    floatx4 az[4], ar[4], axh[4], ahh[4];
    #pragma unroll
    for (int nt = 0; nt < 4; nt++) {
        az[nt].x=0.f; az[nt].y=0.f; az[nt].z=0.f; az[nt].w=0.f;
        ar[nt].x=0.f; ar[nt].y=0.f; ar[nt].z=0.f; ar[nt].w=0.f;
        axh[nt].x=0.f; axh[nt].y=0.f; axh[nt].z=0.f; axh[nt].w=0.f;
        ahh[nt].x=0.f; ahh[nt].y=0.f; ahh[nt].z=0.f; ahh[nt].w=0.f;
    }
    #pragma unroll
    for (int nt = 0; nt < 4; nt++) {
        const bf16_t* bx_z = Wxt + (nt * 16 + l15) * 64 + quad * 8;
        const bf16_t* bh_z = Wht + (nt * 16 + l15) * 64 + quad * 8;
        const bf16_t* bx_r = bx_z + 64 * 64;
        const bf16_t* bh_r = bh_z + 64 * 64;
        const bf16_t* bx_h = bx_z + 128 * 64;
        const bf16_t* bh_h = bh_z + 128 * 64;
        az[nt]  = mfma16(ax[0], *(const bf16x8*)bx_z,        az[nt]);
        az[nt]  = mfma16(ax[1], *(const bf16x8*)(bx_z + 32), az[nt]);
        az[nt]  = mfma16(ah[0], *(const bf16x8*)bh_z,        az[nt]);
        az[nt]  = mfma16(ah[1], *(const bf16x8*)(bh_z + 32), az[nt]);
        ar[nt]  = mfma16(ax[0], *(const bf16x8*)bx_r,        ar[nt]);
        ar[nt]  = mfma16(ax[1], *(const bf16x8*)(bx_r + 32), ar[nt]);
        ar[nt]  = mfma16(ah[0], *(const bf16x8*)bh_r,        ar[nt]);
        ar[nt]  = mfma16(ah[1], *(const bf16x8*)(bh_r + 32), ar[nt]);
        axh[nt] = mfma16(ax[0], *(const bf16x8*)bx_h,        axh[nt]);
        axh[nt] = mfma16(ax[1], *(const bf16x8*)(bx_h + 32), axh[nt]);
        ahh[nt] = mfma16(ah[0], *(const bf16x8*)bh_h,        ahh[nt]);
        ahh[nt] = mfma16(ah[1], *(const bf16x8*)(bh_h + 32), ahh[nt]);
    }

    #pragma unroll
    for (int nt = 0; nt < 4; nt++) {
        int j = nt * 16 + l15;
        float bz = bg[j], brr = bg[64 + j], bh = bg[128 + j];
        #pragma unroll
        for (int r = 0; r < 4; r++) {
            int lrow = wv * 16 + quad * 4 + r;
            int n = n0 + lrow;
            float z  = sigm_f(az[nt][r] + bz);
            float rr = sigm_f(ar[nt][r] + brr);
            float hc = tanh_f(axh[nt][r] + bh + rr * ahh[nt][r]);
            float hold = shd[lrow * 68 + j];
            float hnew = z * hold + (1.f - z) * hc;
            if (LAST) {
                hb2[wv][(quad * 4 + r) * 72 + j] = (bf16_t)hnew;
            } else if (n < NN) {
                hb_out[(size_t)n * 64 + j] = (bf16_t)hnew;
            }
        }
    }

    if (LAST) {
        bf16x8 a0 = *(const bf16x8*)(hb2[wv] + l15 * 72 + quad * 8);
        bf16x8 a1 = *(const bf16x8*)(hb2[wv] + l15 * 72 + quad * 8 + 32);
        floatx4 accR[8];
        #pragma unroll
        for (int nt = 0; nt < 8; nt++) { accR[nt].x=0.f; accR[nt].y=0.f; accR[nt].z=0.f; accR[nt].w=0.f; }
        #pragma unroll
        for (int nt = 0; nt < 8; nt++) {
            bf16x8 b0 = *(const bf16x8*)(Wr1f + ((nt * 2 + 0) * 64 + lane) * 8);
            bf16x8 b1 = *(const bf16x8*)(Wr1f + ((nt * 2 + 1) * 64 + lane) * 8);
            accR[nt] = mfma16(a0, b0, accR[nt]);
            accR[nt] = mfma16(a1, b1, accR[nt]);
        }
        float br1r[8], wr2r[8];
        #pragma unroll
        for (int nt = 0; nt < 8; nt++) {
            br1r[nt] = br1[nt * 16 + l15];
            wr2r[nt] = Wr2[nt * 16 + l15];
        }
        float br2v = br2[0];
        #pragma unroll
        for (int r = 0; r < 4; r++) {
            float p = 0.f;
            #pragma unroll
            for (int nt = 0; nt < 8; nt++)
                p += fmaxf(accR[nt][r] + br1r[nt], 0.f) * wr2r[nt];
            p += __shfl_xor(p, 1, 64);
            p += __shfl_xor(p, 2, 64);
            p += __shfl_xor(p, 4, 64);
            p += __shfl_xor(p, 8, 64);
            if (l15 == 0) {
                int n = n0 + wv * 16 + quad * 4 + r;
                if (n < NN) out[n] = p + br2v;
            }
        }
    }
}

// ---------------------------------------------------------------------------
extern "C" void kernel_launch(void* const* d_in, const int* in_sizes, int n_in,
                              void* d_out, int out_size, void* d_ws, size_t ws_size,
                              hipStream_t stream)
{
    const float* nf  = (const float*)d_in[0];
    const float* ef  = (const float*)d_in[1];
    const int* esrc  = (const int*)d_in[2];
    const int* edst  = (const int*)d_in[3];
    const float* Wm1 = (const float*)d_in[4];
    const float* bm1 = (const float*)d_in[5];
    const float* Wm2 = (const float*)d_in[6];
    const float* bm2 = (const float*)d_in[7];
    const float* Wx  = (const float*)d_in[8];
    const float* Wh  = (const float*)d_in[9];
    const float* bg  = (const float*)d_in[10];
    const float* Wr1 = (const float*)d_in[11];
    const float* br1 = (const float*)d_in[12];
    const float* Wr2 = (const float*)d_in[13];
    const float* br2 = (const float*)d_in[14];

    char* ws = (char*)d_ws;
    bf16_t* hb     = (bf16_t*)(ws);                  // 6,400,000
    bf16_t* W1f    = (bf16_t*)(ws + 6400000);        // 40,960
    bf16_t* W2f    = (bf16_t*)(ws + 6440960);        // 16,384
    bf16_t* Wxt    = (bf16_t*)(ws + 6457344);        // 24,576
    bf16_t* Wht    = (bf16_t*)(ws + 6481920);        // 24,576
    bf16_t* Wr1f   = (bf16_t*)(ws + 6506496);        // 16,384
    int*    srcs   = (int*)(ws + 6522880);           // 1,600,000
    int*    dsts   = (int*)(ws + 8122880);           // 1,600,000
    bf16_t* efpb   = (bf16_t*)(ws + 9722880);        // 6,400,000
    int*    deg    = (int*)(ws + 16122880);          // 200,704
    int*    cursor = (int*)(ws + 16323584);          // 200,704
    bf16_t* mb     = (bf16_t*)(ws + 16524288);       // 51,200,000

    // 1. zero deg (prep's histogram accumulates into it)
    hipMemsetAsync(deg, 0, (size_t)NPAD * 4, stream);
    // 2. prep: hb copy + weight transforms + histogram (fused)
    prep_kernel<<<4928, 256, 0, stream>>>(nf, Wm1, Wm2, Wx, Wh, Wr1, edst,
                                          hb, W1f, W2f, Wxt, Wht, Wr1f, deg);
    // 3. exclusive scan deg -> cursor (single block)
    scan_kernel<<<1, 1024, 0, stream>>>(deg, cursor);
    // 4. scatter into sorted order (cursor -> row-end offsets)
    scatter_kernel<<<(NE + 255) / 256, 256, 0, stream>>>(esrc, edst, ef, cursor,
                                                         srcs, dsts, efpb);
    // 5-8. two message-passing steps, gather-sum fused into GRU
    edge_kernel<<<1024, 256, 0, stream>>>(hb, efpb, srcs, dsts,
                                          W1f, W2f, bm1, bm2, mb);
    gru_kernel<0><<<(NN + 63) / 64, 256, 0, stream>>>(
        mb, deg, cursor, nf, nullptr, hb,
        Wxt, Wht, bg, Wr1f, br1, Wr2, br2, (float*)d_out);
    edge_kernel<<<1024, 256, 0, stream>>>(hb, efpb, srcs, dsts,
                                          W1f, W2f, bm1, bm2, mb);
    gru_kernel<1><<<(NN + 63) / 64, 256, 0, stream>>>(
        mb, deg, cursor, nullptr, hb, nullptr,
        Wxt, Wht, bg, Wr1f, br1, Wr2, br2, (float*)d_out);
}

// Round 14
// 322.920 us; speedup vs baseline: 1.1453x; 1.1453x over previous
//
#include <hip/hip_runtime.h>
#include <hip/hip_bf16.h>

#define NN 50000
#define NE 400000
#define NPAIR 12500        // NE/32: 32 sorted edges per wave-iteration
#define NPAD 50176         // 196*256 scan domain

typedef __bf16 bf16_t;
typedef __bf16 bf16x4 __attribute__((ext_vector_type(4)));
typedef __bf16 bf16x8 __attribute__((ext_vector_type(8)));
typedef float  floatx4 __attribute__((ext_vector_type(4)));

static __device__ __forceinline__ floatx4 mfma16(bf16x8 a, bf16x8 b, floatx4 c) {
    return __builtin_amdgcn_mfma_f32_16x16x32_bf16(a, b, c, 0, 0, 0);
}
static __device__ __forceinline__ float sigm_f(float x) {
    return 1.f / (1.f + __expf(-x));
}
static __device__ __forceinline__ float tanh_f(float x) {
    return 1.f - 2.f / (__expf(2.f * x) + 1.f);
}
static __device__ __forceinline__ bf16x8 cvt8(const float* sp) {
    float4 f0 = *(const float4*)sp;
    float4 f1 = *(const float4*)(sp + 4);
    bf16x8 v;
    v[0] = (bf16_t)f0.x; v[1] = (bf16_t)f0.y; v[2] = (bf16_t)f0.z; v[3] = (bf16_t)f0.w;
    v[4] = (bf16_t)f1.x; v[5] = (bf16_t)f1.y; v[6] = (bf16_t)f1.z; v[7] = (bf16_t)f1.w;
    return v;
}

// ---------------------------------------------------------------------------
// prep (fused: hb copy + weight transforms + edge histogram).
// deg must be zeroed before this kernel (memset precedes in-stream).
// ---------------------------------------------------------------------------
__global__ __launch_bounds__(256) void prep_kernel(
    const float* __restrict__ nf,
    const float* __restrict__ Wm1, const float* __restrict__ Wm2,
    const float* __restrict__ Wx,  const float* __restrict__ Wh,
    const float* __restrict__ Wr1, const int* __restrict__ edst,
    bf16_t* __restrict__ hb,
    bf16_t* __restrict__ W1f, bf16_t* __restrict__ W2f,
    bf16_t* __restrict__ Wxt, bf16_t* __restrict__ Wht,
    bf16_t* __restrict__ Wr1f, int* __restrict__ deg)
{
    int u = blockIdx.x * 256 + threadIdx.x;
    if (u < 800000) {          // hb: 4 elems per thread
        float4 v = *(const float4*)(nf + (size_t)u * 4);
        bf16x4 o;
        o[0] = (bf16_t)v.x; o[1] = (bf16_t)v.y; o[2] = (bf16_t)v.z; o[3] = (bf16_t)v.w;
        *(bf16x4*)(hb + (size_t)u * 4) = o;
        return;
    }
    u -= 800000;
    if (u < 20480) {
        int j = u & 7, l = (u >> 3) & 63, rem = u >> 9;   // rem 0..39
        int ks = rem % 5, nt = rem / 5;
        int n = nt * 16 + (l & 15);
        int k = ks * 32 + (l >> 4) * 8 + j;
        W1f[u] = (k < 136) ? (bf16_t)Wm1[k * 128 + n] : (bf16_t)0.f;
        return;
    }
    u -= 20480;
    if (u < 8192) {
        int j = u & 7, l = (u >> 3) & 63, rem = u >> 9;   // rem 0..15
        int kg = rem & 3, nt = rem >> 2;
        int n = nt * 16 + (l & 15);
        int k = kg * 32 + (l >> 4) * 8 + j;
        W2f[u] = (bf16_t)Wm2[k * 64 + n];
        return;
    }
    u -= 8192;
    if (u < 12288) {
        int n = u >> 6, k = u & 63;
        Wxt[u] = (bf16_t)Wx[k * 192 + n];
        return;
    }
    u -= 12288;
    if (u < 12288) {
        int n = u >> 6, k = u & 63;
        Wht[u] = (bf16_t)Wh[k * 192 + n];
        return;
    }
    u -= 12288;
    if (u < 8192) {            // Wr1f
        int j = u & 7, l = (u >> 3) & 63, rem = u >> 9;   // rem 0..15
        int kg = rem & 1, nt = rem >> 1;
        int n = nt * 16 + (l & 15);
        int k = kg * 32 + (l >> 4) * 8 + j;
        Wr1f[u] = (bf16_t)Wr1[k * 128 + n];
        return;
    }
    u -= 8192;
    if (u < NE) atomicAdd(&deg[edst[u]], 1);   // histogram
}

// ---------------------------------------------------------------------------
// single-dispatch exclusive scan, COALESCED (R13's 1-block/strided version
// ran 77us: 64 lines per wave-load on one CU). 196 blocks; block b reduces
// deg[0..b*256) block-stride (coalesced, L2-hot, ~20MB total redundant) for
// its prefix base, then LDS-scans its own 256-chunk and writes cursor.
// ---------------------------------------------------------------------------
__global__ __launch_bounds__(256) void scan_kernel(
    const int* __restrict__ deg, int* __restrict__ cursor)
{
    __shared__ int s[256];
    const int t = threadIdx.x;
    const int b = blockIdx.x;

    // prefix base = sum deg[0 .. b*256)
    int local = 0;
    for (int i = t; i < b * 256; i += 256) local += deg[i];
    s[t] = local;
    __syncthreads();
    for (int st = 128; st >= 1; st >>= 1) {
        if (t < st) s[t] += s[t + st];
        __syncthreads();
    }
    const int base = s[0];
    __syncthreads();

    // own-chunk exclusive scan
    int v = deg[b * 256 + t];
    s[t] = v;
    __syncthreads();
    for (int st = 1; st < 256; st <<= 1) {
        int add = (t >= st) ? s[t - st] : 0;
        __syncthreads();
        s[t] += add;
        __syncthreads();
    }
    cursor[b * 256 + t] = base + s[t] - v;
}

// ---------------------------------------------------------------------------
// scatter: permute srcs/dsts/ef->bf16 into dst-sorted order.
// cursor ends at row-end offsets (gru uses end-deg for start).
// ---------------------------------------------------------------------------
__global__ __launch_bounds__(256) void scatter_kernel(
    const int* __restrict__ esrc, const int* __restrict__ edst,
    const float* __restrict__ ef,
    int* __restrict__ cursor, int* __restrict__ srcs, int* __restrict__ dsts,
    bf16_t* __restrict__ efpb)
{
    int e = blockIdx.x * 256 + threadIdx.x;
    if (e >= NE) return;
    int d = edst[e];
    int p = atomicAdd(&cursor[d], 1);
    srcs[p] = esrc[e];
    dsts[p] = d;
    float4 a = *(const float4*)(ef + (size_t)e * 8);
    float4 b = *(const float4*)(ef + (size_t)e * 8 + 4);
    bf16x8 v;
    v[0] = (bf16_t)a.x; v[1] = (bf16_t)a.y; v[2] = (bf16_t)a.z; v[3] = (bf16_t)a.w;
    v[4] = (bf16_t)b.x; v[5] = (bf16_t)b.y; v[6] = (bf16_t)b.z; v[7] = (bf16_t)b.w;
    *(bf16x8*)(efpb + (size_t)p * 8) = v;
}

// ---------------------------------------------------------------------------
// edge kernel (R12, unchanged): zero atomics, bf16 m stores in sorted order.
// ---------------------------------------------------------------------------
__global__ __launch_bounds__(256) void edge_kernel(
    const bf16_t* __restrict__ hb, const bf16_t* __restrict__ efpb,
    const int* __restrict__ srcs, const int* __restrict__ dsts,
    const bf16_t* __restrict__ W1f, const bf16_t* __restrict__ W2f,
    const float* __restrict__ b1f, const float* __restrict__ b2f,
    bf16_t* __restrict__ mb)
{
    __shared__ __attribute__((aligned(16))) bf16_t w1s[20480];      // 40960 B
    __shared__ __attribute__((aligned(16))) bf16_t w2s[8192];       // 16384 B
    __shared__ __attribute__((aligned(16))) bf16_t hq[4][32 * 36];  //  9216 B

    const int tid = threadIdx.x;
    {
        const uint4* s1 = (const uint4*)W1f;
        uint4* d1 = (uint4*)w1s;
        #pragma unroll
        for (int i = 0; i < 10; i++) d1[tid + i * 256] = s1[tid + i * 256];
        const uint4* s2 = (const uint4*)W2f;
        uint4* d2 = (uint4*)w2s;
        #pragma unroll
        for (int i = 0; i < 4; i++) d2[tid + i * 256] = s2[tid + i * 256];
    }
    __syncthreads();

    const int lane = tid & 63;
    const int wv   = tid >> 6;
    const int l15  = lane & 15;
    const int quad = lane >> 4;

    float b1r[8], b2r[4];
    #pragma unroll
    for (int nt = 0; nt < 8; nt++) b1r[nt] = b1f[nt * 16 + l15];
    #pragma unroll
    for (int nt = 0; nt < 4; nt++) b2r[nt] = b2f[nt * 16 + l15];

    const int WTOT = gridDim.x * 4;
    int p = blockIdx.x * 4 + wv;

    bf16x8 af0[5], af1[5];
    {
        int base = p * 32;
        int r0 = base + l15, r1 = base + 16 + l15;
        int si0 = srcs[r0], di0 = dsts[r0];
        int si1 = srcs[r1], di1 = dsts[r1];
        const bf16_t* sp0 = hb + (size_t)si0 * 64 + quad * 8;
        const bf16_t* dp0 = hb + (size_t)di0 * 64 + quad * 8;
        const bf16_t* sp1 = hb + (size_t)si1 * 64 + quad * 8;
        const bf16_t* dp1 = hb + (size_t)di1 * 64 + quad * 8;
        af0[0] = *(const bf16x8*)sp0;  af0[1] = *(const bf16x8*)(sp0 + 32);
        af0[2] = *(const bf16x8*)dp0;  af0[3] = *(const bf16x8*)(dp0 + 32);
        af1[0] = *(const bf16x8*)sp1;  af1[1] = *(const bf16x8*)(sp1 + 32);
        af1[2] = *(const bf16x8*)dp1;  af1[3] = *(const bf16x8*)(dp1 + 32);
        if (quad == 0) {
            af0[4] = *(const bf16x8*)(efpb + (size_t)r0 * 8);
            af1[4] = *(const bf16x8*)(efpb + (size_t)r1 * 8);
        } else {
            #pragma unroll
            for (int q = 0; q < 8; q++) { af0[4][q] = (bf16_t)0.f; af1[4][q] = (bf16_t)0.f; }
        }
    }

    while (true) {
        int pn = p + WTOT;
        int pp = (pn < NPAIR) ? pn : p;
        int nbase = pp * 32;
        int nr0 = nbase + l15, nr1 = nbase + 16 + l15;
        int si0n = srcs[nr0], di0n = dsts[nr0];
        int si1n = srcs[nr1], di1n = dsts[nr1];

        floatx4 oa0[4], oa1[4];
        #pragma unroll
        for (int nt = 0; nt < 4; nt++) {
            oa0[nt].x=0.f; oa0[nt].y=0.f; oa0[nt].z=0.f; oa0[nt].w=0.f;
            oa1[nt].x=0.f; oa1[nt].y=0.f; oa1[nt].z=0.f; oa1[nt].w=0.f;
        }

        #pragma unroll
        for (int q = 0; q < 4; q++) {
            floatx4 ac0[2], ac1[2];
            #pragma unroll
            for (int nt = 0; nt < 2; nt++) {
                ac0[nt].x=0.f; ac0[nt].y=0.f; ac0[nt].z=0.f; ac0[nt].w=0.f;
                ac1[nt].x=0.f; ac1[nt].y=0.f; ac1[nt].z=0.f; ac1[nt].w=0.f;
            }
            #pragma unroll
            for (int nt = 0; nt < 2; nt++) {
                int gnt = q * 2 + nt;
                #pragma unroll
                for (int ks = 0; ks < 5; ks++) {
                    bf16x8 b = *(const bf16x8*)(w1s + ((gnt * 5 + ks) * 64 + lane) * 8);
                    ac0[nt] = mfma16(af0[ks], b, ac0[nt]);
                    ac1[nt] = mfma16(af1[ks], b, ac1[nt]);
                }
            }
            #pragma unroll
            for (int nt = 0; nt < 2; nt++) {
                float bb = b1r[q * 2 + nt];
                #pragma unroll
                for (int r = 0; r < 4; r++) {
                    float v0 = fmaxf(ac0[nt][r] + bb, 0.f);
                    float v1 = fmaxf(ac1[nt][r] + bb, 0.f);
                    hq[wv][(quad * 4 + r) * 36 + nt * 16 + l15]      = (bf16_t)v0;
                    hq[wv][(16 + quad * 4 + r) * 36 + nt * 16 + l15] = (bf16_t)v1;
                }
            }
            bf16x8 hf0 = *(const bf16x8*)(hq[wv] + l15 * 36 + quad * 8);
            bf16x8 hf1 = *(const bf16x8*)(hq[wv] + (16 + l15) * 36 + quad * 8);
            #pragma unroll
            for (int nt = 0; nt < 4; nt++) {
                bf16x8 w2 = *(const bf16x8*)(w2s + ((nt * 4 + q) * 64 + lane) * 8);
                oa0[nt] = mfma16(hf0, w2, oa0[nt]);
                oa1[nt] = mfma16(hf1, w2, oa1[nt]);
            }
        }

        // prefetch next-pair A fragments BEFORE the store epilogue
        int base = p * 32;
        {
            const bf16_t* sp0 = hb + (size_t)si0n * 64 + quad * 8;
            const bf16_t* dp0 = hb + (size_t)di0n * 64 + quad * 8;
            const bf16_t* sp1 = hb + (size_t)si1n * 64 + quad * 8;
            const bf16_t* dp1 = hb + (size_t)di1n * 64 + quad * 8;
            af0[0] = *(const bf16x8*)sp0;  af0[1] = *(const bf16x8*)(sp0 + 32);
            af0[2] = *(const bf16x8*)dp0;  af0[3] = *(const bf16x8*)(dp0 + 32);
            af1[0] = *(const bf16x8*)sp1;  af1[1] = *(const bf16x8*)(sp1 + 32);
            af1[2] = *(const bf16x8*)dp1;  af1[3] = *(const bf16x8*)(dp1 + 32);
            if (quad == 0) {
                af0[4] = *(const bf16x8*)(efpb + (size_t)nr0 * 8);
                af1[4] = *(const bf16x8*)(efpb + (size_t)nr1 * 8);
            }
        }

        #pragma unroll
        for (int nt = 0; nt < 4; nt++) {
            int col = nt * 16 + l15;
            float bb = b2r[nt];
            #pragma unroll
            for (int r = 0; r < 4; r++) {
                int row0 = base + quad * 4 + r;
                int row1 = base + 16 + quad * 4 + r;
                mb[(size_t)row0 * 64 + col] = (bf16_t)(oa0[nt][r] + bb);
                mb[(size_t)row1 * 64 + col] = (bf16_t)(oa1[nt][r] + bb);
            }
        }

        if (pn >= NPAIR) break;
        p = pn;
    }
}

// ---------------------------------------------------------------------------
// GRU (MFMA) with fused CSR gather-sum (R13). 64 nodes/block, 16/wave.
// LAST=0: h source fp32 (nf), emits bf16 hb. LAST=1: h source bf16 hb,
// fused readout MLP -> out.
// ---------------------------------------------------------------------------
template<int LAST>
__global__ __launch_bounds__(256) void gru_kernel(
    const bf16_t* __restrict__ mb, const int* __restrict__ deg,
    const int* __restrict__ cursor,
    const float* __restrict__ hf, const bf16_t* __restrict__ hbin,
    bf16_t* __restrict__ hb_out,
    const bf16_t* __restrict__ Wxt, const bf16_t* __restrict__ Wht,
    const float* __restrict__ bg,
    const bf16_t* __restrict__ Wr1f, const float* __restrict__ br1,
    const float* __restrict__ Wr2, const float* __restrict__ br2,
    float* __restrict__ out)
{
    __shared__ __attribute__((aligned(16))) float  shd[64 * 68];    // 17408 B
    __shared__ __attribute__((aligned(16))) bf16_t hb2[4][16 * 72]; //  9216 B
    const int tid = threadIdx.x;
    const int n0  = blockIdx.x * 64;

    for (int idx = tid; idx < 64 * 16; idx += 256) {
        int i = idx >> 4, c = (idx & 15) * 4;
        int n = n0 + i; if (n >= NN) n = NN - 1;
        if (LAST == 0) {
            *(float4*)&shd[i * 68 + c] = *(const float4*)(hf + (size_t)n * 64 + c);
        } else {
            bf16x4 v = *(const bf16x4*)(hbin + (size_t)n * 64 + c);
            shd[i * 68 + c + 0] = (float)v[0];
            shd[i * 68 + c + 1] = (float)v[1];
            shd[i * 68 + c + 2] = (float)v[2];
            shd[i * 68 + c + 3] = (float)v[3];
        }
    }
    __syncthreads();

    const int lane = tid & 63;
    const int wv   = tid >> 6;
    const int l15  = lane & 15;
    const int quad = lane >> 4;
    const int rowA = wv * 16 + l15;
    int nA = n0 + rowA; if (nA >= NN) nA = NN - 1;

    // fused CSR gather-sum: agg[nA][quad*8..] and [32+quad*8..]
    bf16x8 ax[2];
    {
        int en = cursor[nA];
        int st = en - deg[nA];
        float fa0[8], fa1[8];
        #pragma unroll
        for (int j = 0; j < 8; j++) { fa0[j] = 0.f; fa1[j] = 0.f; }
        #pragma unroll 1
        for (int e = st; e < en; e++) {
            bf16x8 v0 = *(const bf16x8*)(mb + (size_t)e * 64 + quad * 8);
            bf16x8 v1 = *(const bf16x8*)(mb + (size_t)e * 64 + 32 + quad * 8);
            #pragma unroll
            for (int j = 0; j < 8; j++) {
                fa0[j] += (float)v0[j];
                fa1[j] += (float)v1[j];
            }
        }
        #pragma unroll
        for (int j = 0; j < 8; j++) {
            ax[0][j] = (bf16_t)fa0[j];
            ax[1][j] = (bf16_t)fa1[j];
        }
    }

    bf16x8 ah[2];
    {
        const float* hp = shd + rowA * 68 + quad * 8;
        ah[0] = cvt8(hp);
        ah[1] = cvt8(hp + 32);
    }

    floatx4 az[4], ar[4], axh[4], ahh[4];
    #pragma unroll
    for (int nt = 0; nt < 4; nt++) {
        az[nt].x=0.f; az[nt].y=0.f; az[nt].z=0.f; az[nt].w=0.f;
        ar[nt].x=0.f; ar[nt].y=0.f; ar[nt].z=0.f; ar[nt].w=0.f;
        axh[nt].x=0.f; axh[nt].y=0.f; axh[nt].z=0.f; axh[nt].w=0.f;
        ahh[nt].x=0.f; ahh[nt].y=0.f; ahh[nt].z=0.f; ahh[nt].w=0.f;
    }
    #pragma unroll
    for (int nt = 0; nt < 4; nt++) {
        const bf16_t* bx_z = Wxt + (nt * 16 + l15) * 64 + quad * 8;
        const bf16_t* bh_z = Wht + (nt * 16 + l15) * 64 + quad * 8;
        const bf16_t* bx_r = bx_z + 64 * 64;
        const bf16_t* bh_r = bh_z + 64 * 64;
        const bf16_t* bx_h = bx_z + 128 * 64;
        const bf16_t* bh_h = bh_z + 128 * 64;
        az[nt]  = mfma16(ax[0], *(const bf16x8*)bx_z,        az[nt]);
        az[nt]  = mfma16(ax[1], *(const bf16x8*)(bx_z + 32), az[nt]);
        az[nt]  = mfma16(ah[0], *(const bf16x8*)bh_z,        az[nt]);
        az[nt]  = mfma16(ah[1], *(const bf16x8*)(bh_z + 32), az[nt]);
        ar[nt]  = mfma16(ax[0], *(const bf16x8*)bx_r,        ar[nt]);
        ar[nt]  = mfma16(ax[1], *(const bf16x8*)(bx_r + 32), ar[nt]);
        ar[nt]  = mfma16(ah[0], *(const bf16x8*)bh_r,        ar[nt]);
        ar[nt]  = mfma16(ah[1], *(const bf16x8*)(bh_r + 32), ar[nt]);
        axh[nt] = mfma16(ax[0], *(const bf16x8*)bx_h,        axh[nt]);
        axh[nt] = mfma16(ax[1], *(const bf16x8*)(bx_h + 32), axh[nt]);
        ahh[nt] = mfma16(ah[0], *(const bf16x8*)bh_h,        ahh[nt]);
        ahh[nt] = mfma16(ah[1], *(const bf16x8*)(bh_h + 32), ahh[nt]);
    }

    #pragma unroll
    for (int nt = 0; nt < 4; nt++) {
        int j = nt * 16 + l15;
        float bz = bg[j], brr = bg[64 + j], bh = bg[128 + j];
        #pragma unroll
        for (int r = 0; r < 4; r++) {
            int lrow = wv * 16 + quad * 4 + r;
            int n = n0 + lrow;
            float z  = sigm_f(az[nt][r] + bz);
            float rr = sigm_f(ar[nt][r] + brr);
            float hc = tanh_f(axh[nt][r] + bh + rr * ahh[nt][r]);
            float hold = shd[lrow * 68 + j];
            float hnew = z * hold + (1.f - z) * hc;
            if (LAST) {
                hb2[wv][(quad * 4 + r) * 72 + j] = (bf16_t)hnew;
            } else if (n < NN) {
                hb_out[(size_t)n * 64 + j] = (bf16_t)hnew;
            }
        }
    }

    if (LAST) {
        bf16x8 a0 = *(const bf16x8*)(hb2[wv] + l15 * 72 + quad * 8);
        bf16x8 a1 = *(const bf16x8*)(hb2[wv] + l15 * 72 + quad * 8 + 32);
        floatx4 accR[8];
        #pragma unroll
        for (int nt = 0; nt < 8; nt++) { accR[nt].x=0.f; accR[nt].y=0.f; accR[nt].z=0.f; accR[nt].w=0.f; }
        #pragma unroll
        for (int nt = 0; nt < 8; nt++) {
            bf16x8 b0 = *(const bf16x8*)(Wr1f + ((nt * 2 + 0) * 64 + lane) * 8);
            bf16x8 b1 = *(const bf16x8*)(Wr1f + ((nt * 2 + 1) * 64 + lane) * 8);
            accR[nt] = mfma16(a0, b0, accR[nt]);
            accR[nt] = mfma16(a1, b1, accR[nt]);
        }
        float br1r[8], wr2r[8];
        #pragma unroll
        for (int nt = 0; nt < 8; nt++) {
            br1r[nt] = br1[nt * 16 + l15];
            wr2r[nt] = Wr2[nt * 16 + l15];
        }
        float br2v = br2[0];
        #pragma unroll
        for (int r = 0; r < 4; r++) {
            float p = 0.f;
            #pragma unroll
            for (int nt = 0; nt < 8; nt++)
                p += fmaxf(accR[nt][r] + br1r[nt], 0.f) * wr2r[nt];
            p += __shfl_xor(p, 1, 64);
            p += __shfl_xor(p, 2, 64);
            p += __shfl_xor(p, 4, 64);
            p += __shfl_xor(p, 8, 64);
            if (l15 == 0) {
                int n = n0 + wv * 16 + quad * 4 + r;
                if (n < NN) out[n] = p + br2v;
            }
        }
    }
}

// ---------------------------------------------------------------------------
extern "C" void kernel_launch(void* const* d_in, const int* in_sizes, int n_in,
                              void* d_out, int out_size, void* d_ws, size_t ws_size,
                              hipStream_t stream)
{
    const float* nf  = (const float*)d_in[0];
    const float* ef  = (const float*)d_in[1];
    const int* esrc  = (const int*)d_in[2];
    const int* edst  = (const int*)d_in[3];
    const float* Wm1 = (const float*)d_in[4];
    const float* bm1 = (const float*)d_in[5];
    const float* Wm2 = (const float*)d_in[6];
    const float* bm2 = (const float*)d_in[7];
    const float* Wx  = (const float*)d_in[8];
    const float* Wh  = (const float*)d_in[9];
    const float* bg  = (const float*)d_in[10];
    const float* Wr1 = (const float*)d_in[11];
    const float* br1 = (const float*)d_in[12];
    const float* Wr2 = (const float*)d_in[13];
    const float* br2 = (const float*)d_in[14];

    char* ws = (char*)d_ws;
    bf16_t* hb     = (bf16_t*)(ws);                  // 6,400,000
    bf16_t* W1f    = (bf16_t*)(ws + 6400000);        // 40,960
    bf16_t* W2f    = (bf16_t*)(ws + 6440960);        // 16,384
    bf16_t* Wxt    = (bf16_t*)(ws + 6457344);        // 24,576
    bf16_t* Wht    = (bf16_t*)(ws + 6481920);        // 24,576
    bf16_t* Wr1f   = (bf16_t*)(ws + 6506496);        // 16,384
    int*    srcs   = (int*)(ws + 6522880);           // 1,600,000
    int*    dsts   = (int*)(ws + 8122880);           // 1,600,000
    bf16_t* efpb   = (bf16_t*)(ws + 9722880);        // 6,400,000
    int*    deg    = (int*)(ws + 16122880);          // 200,704
    int*    cursor = (int*)(ws + 16323584);          // 200,704
    bf16_t* mb     = (bf16_t*)(ws + 16524288);       // 51,200,000

    // 1. zero deg (prep's histogram accumulates into it)
    hipMemsetAsync(deg, 0, (size_t)NPAD * 4, stream);
    // 2. prep: hb copy + weight transforms + histogram (fused)
    prep_kernel<<<4928, 256, 0, stream>>>(nf, Wm1, Wm2, Wx, Wh, Wr1, edst,
                                          hb, W1f, W2f, Wxt, Wht, Wr1f, deg);
    // 3. exclusive scan deg -> cursor (196 blocks, coalesced)
    scan_kernel<<<196, 256, 0, stream>>>(deg, cursor);
    // 4. scatter into sorted order (cursor -> row-end offsets)
    scatter_kernel<<<(NE + 255) / 256, 256, 0, stream>>>(esrc, edst, ef, cursor,
                                                         srcs, dsts, efpb);
    // 5-8. two message-passing steps, gather-sum fused into GRU
    edge_kernel<<<1024, 256, 0, stream>>>(hb, efpb, srcs, dsts,
                                          W1f, W2f, bm1, bm2, mb);
    gru_kernel<0><<<(NN + 63) / 64, 256, 0, stream>>>(
        mb, deg, cursor, nf, nullptr, hb,
        Wxt, Wht, bg, Wr1f, br1, Wr2, br2, (float*)d_out);
    edge_kernel<<<1024, 256, 0, stream>>>(hb, efpb, srcs, dsts,
                                          W1f, W2f, bm1, bm2, mb);
    gru_kernel<1><<<(NN + 63) / 64, 256, 0, stream>>>(
        mb, deg, cursor, nullptr, hb, nullptr,
        Wxt, Wht, bg, Wr1f, br1, Wr2, br2, (float*)d_out);
}